// Round 7
// baseline (290.640 us; speedup 1.0000x reference)
//
#include <hip/hip_runtime.h>
#include <hip/hip_bf16.h>

typedef __attribute__((ext_vector_type(8))) short bf16x8;
typedef __attribute__((ext_vector_type(4))) float f32x4;

#define NBLK 256   // blocks; 512 threads each; 1 block/CU (88 KB LDS)

__device__ __forceinline__ unsigned short f2bf(float f) {
    unsigned u = __float_as_uint(f);
    return (unsigned short)((u + 0x7fffu + ((u >> 16) & 1u)) >> 16);
}

__device__ __forceinline__ bf16x8 pack8(float4 x, float4 y) {
    bf16x8 r;
    r[0] = (short)f2bf(x.x); r[1] = (short)f2bf(x.y);
    r[2] = (short)f2bf(x.z); r[3] = (short)f2bf(x.w);
    r[4] = (short)f2bf(y.x); r[5] = (short)f2bf(y.y);
    r[6] = (short)f2bf(y.z); r[7] = (short)f2bf(y.w);
    return r;
}

__device__ __forceinline__ float ftanh(float x) {
    float e = __expf(2.f * x);
    return 1.f - 2.f / (e + 1.f);
}

// One fused kernel. Edges processed in order, 32 per wave-supertile (2 MFMA
// tiles of 16). All 11 matrices (10 W_t + lin_w) staged in LDS as bf16
// A-fragments; per tile compute z_m = M_m * d for all 11, per-lane select
// z_{type(edge)} for the tanh path (m=10 is lin, always kept).
// Fragment layout (verified rounds 1-5): A row = lane&15 (output row within
// 16-block), k = (lane>>4)*8 + j; B col = lane&15 (edge), same k mapping;
// D col = lane&15 (edge), row = (lane>>4)*4 + r  -> float4 store per nt.
// NOTE: stores must be REGULAR (write-back L2 merges the 4 partial-line
// writes per 64B line); nontemporal stores caused 14x HBM write
// amplification (round 6: WRITE_SIZE 468 MB vs 32 MB ideal).
__global__ __launch_bounds__(512, 2) void k_fused(
    const int* __restrict__ ij, const float* __restrict__ desc,
    const float* __restrict__ layer1, const float* __restrict__ lin_w,
    const float* __restrict__ lin_b, float* __restrict__ out, int E) {

    __shared__ __align__(16) short wsm[11 * 512 * 8];   // 88 KiB

    // ---- stage all weights into LDS (bf16 MFMA A-fragment layout) ----
    for (int idx = threadIdx.x; idx < 11 * 512; idx += 512) {
        const int m = idx >> 9;          // matrix 0..10 (10 = lin_w)
        const int fl = idx & 511;        // frag-lane
        const int fi = fl >> 6, l = fl & 63;
        const int nt = fi >> 1, kk = fi & 1;
        const float* src = (m < 10) ? (layer1 + m * 4096) : lin_w;
        const float* sp = src + (nt * 16 + (l & 15)) * 64 + kk * 32 + (l >> 4) * 8;
        float4 x = *(const float4*)sp;
        float4 y = *(const float4*)(sp + 4);
        *(bf16x8*)(&wsm[idx * 8]) = pack8(x, y);
    }

    const int lane = threadIdx.x & 63;
    const int col = lane & 15;
    const int g = lane >> 4;
    const int kb = g * 8;

    float4 bias[4];
    #pragma unroll
    for (int nt = 0; nt < 4; ++nt) bias[nt] = *(const float4*)(lin_b + nt * 16 + g * 4);

    __syncthreads();

    const int gw = blockIdx.x * 8 + (threadIdx.x >> 6);
    const int nst = (E + 31) >> 5;       // 32-edge supertiles
    for (int s = gw; s < nst; s += NBLK * 8) {
        const int jb = s * 32;
        const int eA = jb + col, eB = jb + 16 + col;
        const int eAc = min(eA, E - 1), eBc = min(eB, E - 1);
        const int tyA = ij[eAc], tyB = ij[eBc];

        bf16x8 bA[2], bB[2];
        {
            const float* dp = desc + (size_t)eAc * 64 + kb;
            float4 x0 = *(const float4*)dp,        y0 = *(const float4*)(dp + 4);
            float4 x1 = *(const float4*)(dp + 32), y1 = *(const float4*)(dp + 36);
            bA[0] = pack8(x0, y0); bA[1] = pack8(x1, y1);
            const float* dq = desc + (size_t)eBc * 64 + kb;
            float4 p0 = *(const float4*)dq,        q0 = *(const float4*)(dq + 4);
            float4 p1 = *(const float4*)(dq + 32), q1 = *(const float4*)(dq + 36);
            bB[0] = pack8(p0, q0); bB[1] = pack8(p1, q1);
        }

        f32x4 aWA[4], aWB[4], zA[4], zB[4];
        #pragma unroll
        for (int nt = 0; nt < 4; ++nt) {
            aWA[nt] = (f32x4){0.f, 0.f, 0.f, 0.f};
            aWB[nt] = (f32x4){0.f, 0.f, 0.f, 0.f};
        }

        for (int m = 0; m < 11; ++m) {
            #pragma unroll
            for (int nt = 0; nt < 4; ++nt) {
                const bf16x8 f0 = *(const bf16x8*)(&wsm[((m * 8 + nt * 2 + 0) * 64 + lane) * 8]);
                const bf16x8 f1 = *(const bf16x8*)(&wsm[((m * 8 + nt * 2 + 1) * 64 + lane) * 8]);
                f32x4 z = {0.f, 0.f, 0.f, 0.f};
                z = __builtin_amdgcn_mfma_f32_16x16x32_bf16(f0, bA[0], z, 0, 0, 0);
                z = __builtin_amdgcn_mfma_f32_16x16x32_bf16(f1, bA[1], z, 0, 0, 0);
                zA[nt] = z;
                f32x4 y = {0.f, 0.f, 0.f, 0.f};
                y = __builtin_amdgcn_mfma_f32_16x16x32_bf16(f0, bB[0], y, 0, 0, 0);
                y = __builtin_amdgcn_mfma_f32_16x16x32_bf16(f1, bB[1], y, 0, 0, 0);
                zB[nt] = y;
            }
            if (m < 10) {
                #pragma unroll
                for (int nt = 0; nt < 4; ++nt) {
                    aWA[nt] = (tyA == m) ? zA[nt] : aWA[nt];
                    aWB[nt] = (tyB == m) ? zB[nt] : aWB[nt];
                }
            }
        }

        // epilogue: zA/zB now hold the lin results (m = 10)
        if (eA < E) {
            float* op = out + (size_t)eA * 64 + g * 4;
            #pragma unroll
            for (int nt = 0; nt < 4; ++nt) {
                f32x4 r;
                r[0] = ftanh(aWA[nt][0]) + zA[nt][0] + bias[nt].x;
                r[1] = ftanh(aWA[nt][1]) + zA[nt][1] + bias[nt].y;
                r[2] = ftanh(aWA[nt][2]) + zA[nt][2] + bias[nt].z;
                r[3] = ftanh(aWA[nt][3]) + zA[nt][3] + bias[nt].w;
                *(f32x4*)(op + nt * 16) = r;
            }
        }
        if (eB < E) {
            float* op = out + (size_t)eB * 64 + g * 4;
            #pragma unroll
            for (int nt = 0; nt < 4; ++nt) {
                f32x4 r;
                r[0] = ftanh(aWB[nt][0]) + zB[nt][0] + bias[nt].x;
                r[1] = ftanh(aWB[nt][1]) + zB[nt][1] + bias[nt].y;
                r[2] = ftanh(aWB[nt][2]) + zB[nt][2] + bias[nt].z;
                r[3] = ftanh(aWB[nt][3]) + zB[nt][3] + bias[nt].w;
                *(f32x4*)(op + nt * 16) = r;
            }
        }
    }
}

extern "C" void kernel_launch(void* const* d_in, const int* in_sizes, int n_in,
                              void* d_out, int out_size, void* d_ws, size_t ws_size,
                              hipStream_t stream) {
    const int* ij = (const int*)d_in[0];
    const float* desc = (const float*)d_in[1];
    const float* layer1 = (const float*)d_in[2];
    const float* lin_w = (const float*)d_in[3];
    const float* lin_b = (const float*)d_in[4];
    float* out = (float*)d_out;
    const int E = in_sizes[0];

    k_fused<<<NBLK, 512, 0, stream>>>(ij, desc, layer1, lin_w, lin_b, out, E);
}

// Round 8
// 86.257 us; speedup vs baseline: 3.3695x; 3.3695x over previous
//
#include <hip/hip_runtime.h>
#include <hip/hip_bf16.h>

typedef __attribute__((ext_vector_type(8))) short bf16x8;
typedef __attribute__((ext_vector_type(4))) float f32x4;

#define NBLK 256   // blocks; 512 threads each; 1 block/CU (88 KB LDS)

__device__ __forceinline__ unsigned short f2bf(float f) {
    unsigned u = __float_as_uint(f);
    return (unsigned short)((u + 0x7fffu + ((u >> 16) & 1u)) >> 16);
}

__device__ __forceinline__ bf16x8 pack8(float4 x, float4 y) {
    bf16x8 r;
    r[0] = (short)f2bf(x.x); r[1] = (short)f2bf(x.y);
    r[2] = (short)f2bf(x.z); r[3] = (short)f2bf(x.w);
    r[4] = (short)f2bf(y.x); r[5] = (short)f2bf(y.y);
    r[6] = (short)f2bf(y.z); r[7] = (short)f2bf(y.w);
    return r;
}

__device__ __forceinline__ float ftanh(float x) {
    float e = __expf(2.f * x);
    return 1.f - 2.f / (e + 1.f);
}

// Fused kernel, masked-B accumulation: out_e = tanh(Σ_m mfma(W_m, [ty_e==m]·d_e))
// + (L·d_e + b). One accumulator per path (zero B-frags add exact 0), so the
// live register set stays ~100 (round-6/7's 16-accumulator + select-chain form
// showed symmetric FETCH/WRITE ~430 MB — scratch-spill signature).
// Fragment layout (verified rounds 1-5): A row = lane&15, k = (lane>>4)*8+j;
// B col = lane&15 (edge), same k mapping; D col = lane&15 (edge),
// row = (lane>>4)*4 + r -> one f32x4 store per nt (proven clean in round 4).
__global__ __launch_bounds__(512, 1) void k_fused(
    const int* __restrict__ ij, const float* __restrict__ desc,
    const float* __restrict__ layer1, const float* __restrict__ lin_w,
    const float* __restrict__ lin_b, float* __restrict__ out, int E) {

    __shared__ __align__(16) short wsm[11 * 512 * 8];   // 88 KiB; m=10 is lin_w

    for (int idx = threadIdx.x; idx < 11 * 512; idx += 512) {
        const int m = idx >> 9;
        const int fl = idx & 511;
        const int fi = fl >> 6, l = fl & 63;
        const int nt = fi >> 1, kk = fi & 1;
        const float* src = (m < 10) ? (layer1 + m * 4096) : lin_w;
        const float* sp = src + (nt * 16 + (l & 15)) * 64 + kk * 32 + (l >> 4) * 8;
        float4 x = *(const float4*)sp;
        float4 y = *(const float4*)(sp + 4);
        *(bf16x8*)(&wsm[idx * 8]) = pack8(x, y);
    }

    const int lane = threadIdx.x & 63;
    const int col = lane & 15;
    const int g = lane >> 4;
    const int kb = g * 8;

    float4 bias[4];
    #pragma unroll
    for (int nt = 0; nt < 4; ++nt) bias[nt] = *(const float4*)(lin_b + nt * 16 + g * 4);

    __syncthreads();

    const bf16x8 zero8 = {0, 0, 0, 0, 0, 0, 0, 0};
    const int gw = blockIdx.x * 8 + (threadIdx.x >> 6);
    const int nst = (E + 31) >> 5;       // 32-edge supertiles
    for (int s = gw; s < nst; s += NBLK * 8) {
        const int jb = s * 32;
        const int eA = jb + col, eB = jb + 16 + col;
        const int eAc = min(eA, E - 1), eBc = min(eB, E - 1);
        const int tyA = ij[eAc], tyB = ij[eBc];

        bf16x8 bA[2], bB[2];
        {
            const float* dp = desc + (size_t)eAc * 64 + kb;
            float4 x0 = *(const float4*)dp,        y0 = *(const float4*)(dp + 4);
            float4 x1 = *(const float4*)(dp + 32), y1 = *(const float4*)(dp + 36);
            bA[0] = pack8(x0, y0); bA[1] = pack8(x1, y1);
            const float* dq = desc + (size_t)eBc * 64 + kb;
            float4 p0 = *(const float4*)dq,        q0 = *(const float4*)(dq + 4);
            float4 p1 = *(const float4*)(dq + 32), q1 = *(const float4*)(dq + 36);
            bB[0] = pack8(p0, q0); bB[1] = pack8(p1, q1);
        }

        // lin path (m = 10 fragments, unmasked)
        f32x4 zLA[4], zLB[4], zWA[4], zWB[4];
        #pragma unroll
        for (int nt = 0; nt < 4; ++nt) {
            const bf16x8 f0 = *(const bf16x8*)(&wsm[((10 * 8 + nt * 2 + 0) * 64 + lane) * 8]);
            const bf16x8 f1 = *(const bf16x8*)(&wsm[((10 * 8 + nt * 2 + 1) * 64 + lane) * 8]);
            f32x4 z = {0.f, 0.f, 0.f, 0.f};
            z = __builtin_amdgcn_mfma_f32_16x16x32_bf16(f0, bA[0], z, 0, 0, 0);
            z = __builtin_amdgcn_mfma_f32_16x16x32_bf16(f1, bA[1], z, 0, 0, 0);
            zLA[nt] = z;
            f32x4 y = {0.f, 0.f, 0.f, 0.f};
            y = __builtin_amdgcn_mfma_f32_16x16x32_bf16(f0, bB[0], y, 0, 0, 0);
            y = __builtin_amdgcn_mfma_f32_16x16x32_bf16(f1, bB[1], y, 0, 0, 0);
            zLB[nt] = y;
            zWA[nt] = (f32x4){0.f, 0.f, 0.f, 0.f};
            zWB[nt] = (f32x4){0.f, 0.f, 0.f, 0.f};
        }

        // W path: masked-B accumulation over the 10 types
        for (int m = 0; m < 10; ++m) {
            const bf16x8 mA0 = (tyA == m) ? bA[0] : zero8;
            const bf16x8 mA1 = (tyA == m) ? bA[1] : zero8;
            const bf16x8 mB0 = (tyB == m) ? bB[0] : zero8;
            const bf16x8 mB1 = (tyB == m) ? bB[1] : zero8;
            #pragma unroll
            for (int nt = 0; nt < 4; ++nt) {
                const bf16x8 f0 = *(const bf16x8*)(&wsm[((m * 8 + nt * 2 + 0) * 64 + lane) * 8]);
                const bf16x8 f1 = *(const bf16x8*)(&wsm[((m * 8 + nt * 2 + 1) * 64 + lane) * 8]);
                zWA[nt] = __builtin_amdgcn_mfma_f32_16x16x32_bf16(f0, mA0, zWA[nt], 0, 0, 0);
                zWA[nt] = __builtin_amdgcn_mfma_f32_16x16x32_bf16(f1, mA1, zWA[nt], 0, 0, 0);
                zWB[nt] = __builtin_amdgcn_mfma_f32_16x16x32_bf16(f0, mB0, zWB[nt], 0, 0, 0);
                zWB[nt] = __builtin_amdgcn_mfma_f32_16x16x32_bf16(f1, mB1, zWB[nt], 0, 0, 0);
            }
        }

        if (eA < E) {
            float* op = out + (size_t)eA * 64 + g * 4;
            #pragma unroll
            for (int nt = 0; nt < 4; ++nt) {
                f32x4 r;
                r[0] = ftanh(zWA[nt][0]) + zLA[nt][0] + bias[nt].x;
                r[1] = ftanh(zWA[nt][1]) + zLA[nt][1] + bias[nt].y;
                r[2] = ftanh(zWA[nt][2]) + zLA[nt][2] + bias[nt].z;
                r[3] = ftanh(zWA[nt][3]) + zLA[nt][3] + bias[nt].w;
                *(f32x4*)(op + nt * 16) = r;
            }
        }
        if (eB < E) {
            float* op = out + (size_t)eB * 64 + g * 4;
            #pragma unroll
            for (int nt = 0; nt < 4; ++nt) {
                f32x4 r;
                r[0] = ftanh(zWB[nt][0]) + zLB[nt][0] + bias[nt].x;
                r[1] = ftanh(zWB[nt][1]) + zLB[nt][1] + bias[nt].y;
                r[2] = ftanh(zWB[nt][2]) + zLB[nt][2] + bias[nt].z;
                r[3] = ftanh(zWB[nt][3]) + zLB[nt][3] + bias[nt].w;
                *(f32x4*)(op + nt * 16) = r;
            }
        }
    }
}

extern "C" void kernel_launch(void* const* d_in, const int* in_sizes, int n_in,
                              void* d_out, int out_size, void* d_ws, size_t ws_size,
                              hipStream_t stream) {
    const int* ij = (const int*)d_in[0];
    const float* desc = (const float*)d_in[1];
    const float* layer1 = (const float*)d_in[2];
    const float* lin_w = (const float*)d_in[3];
    const float* lin_b = (const float*)d_in[4];
    float* out = (float*)d_out;
    const int E = in_sizes[0];

    k_fused<<<NBLK, 512, 0, stream>>>(ij, desc, layer1, lin_w, lin_b, out, E);
}

// Round 9
// 32.067 us; speedup vs baseline: 9.0635x; 2.6899x over previous
//
#include <hip/hip_runtime.h>
#include <hip/hip_bf16.h>

typedef __attribute__((ext_vector_type(8))) short bf16x8;
typedef __attribute__((ext_vector_type(4))) float f32x4;

#define NBLK 256   // blocks; 512 threads each; 1 block/CU (88 KB LDS)

__device__ __forceinline__ unsigned short f2bf(float f) {
    unsigned u = __float_as_uint(f);
    return (unsigned short)((u + 0x7fffu + ((u >> 16) & 1u)) >> 16);
}

__device__ __forceinline__ bf16x8 pack8(float4 x, float4 y) {
    bf16x8 r;
    r[0] = (short)f2bf(x.x); r[1] = (short)f2bf(x.y);
    r[2] = (short)f2bf(x.z); r[3] = (short)f2bf(x.w);
    r[4] = (short)f2bf(y.x); r[5] = (short)f2bf(y.y);
    r[6] = (short)f2bf(y.z); r[7] = (short)f2bf(y.w);
    return r;
}

__device__ __forceinline__ float ftanh(float x) {
    float e = __expf(2.f * x);
    return 1.f - 2.f / (e + 1.f);
}

// Fused kernel, masked-B accumulation, PER-NT OUTER LOOP (register-minimal).
// out_e[nt] = tanh(Σ_m mfma(W_m[nt], [ty_e==m]·d_e)) + (L[nt]·d_e + b[nt]).
// Only 4 f32x4 accumulators live at any time; epilogue+store inside the nt
// iteration so they die immediately. #pragma unroll 1 on m/nt loops stops the
// scheduler from hoisting all fragment ds_reads (rounds 6-8: live-set overflow
// → scratch spill → symmetric FETCH/WRITE excess of 110-420 MB).
// Fragment layout (verified rounds 1-5): A row = lane&15, k = (lane>>4)*8+j;
// B col = lane&15 (edge), same k; D col = lane&15 (edge), row = (lane>>4)*4+r.
__global__ __launch_bounds__(512, 1) void k_fused(
    const int* __restrict__ ij, const float* __restrict__ desc,
    const float* __restrict__ layer1, const float* __restrict__ lin_w,
    const float* __restrict__ lin_b, float* __restrict__ out, int E) {

    __shared__ __align__(16) short wsm[11 * 512 * 8];   // 88 KiB; m=10 is lin_w

    for (int idx = threadIdx.x; idx < 11 * 512; idx += 512) {
        const int m = idx >> 9;
        const int fl = idx & 511;
        const int fi = fl >> 6, l = fl & 63;
        const int nt = fi >> 1, kk = fi & 1;
        const float* src = (m < 10) ? (layer1 + m * 4096) : lin_w;
        const float* sp = src + (nt * 16 + (l & 15)) * 64 + kk * 32 + (l >> 4) * 8;
        float4 x = *(const float4*)sp;
        float4 y = *(const float4*)(sp + 4);
        *(bf16x8*)(&wsm[idx * 8]) = pack8(x, y);
    }

    const int lane = threadIdx.x & 63;
    const int col = lane & 15;
    const int g = lane >> 4;
    const int kb = g * 8;

    __syncthreads();

    const bf16x8 zero8 = {0, 0, 0, 0, 0, 0, 0, 0};
    const int gw = blockIdx.x * 8 + (threadIdx.x >> 6);
    const int nst = (E + 31) >> 5;       // 32-edge supertiles
    for (int s = gw; s < nst; s += NBLK * 8) {
        const int jb = s * 32;
        const int eA = jb + col, eB = jb + 16 + col;
        const int eAc = min(eA, E - 1), eBc = min(eB, E - 1);
        const int tyA = ij[eAc], tyB = ij[eBc];

        bf16x8 bA[2], bB[2];
        {
            const float* dp = desc + (size_t)eAc * 64 + kb;
            float4 x0 = *(const float4*)dp,        y0 = *(const float4*)(dp + 4);
            float4 x1 = *(const float4*)(dp + 32), y1 = *(const float4*)(dp + 36);
            bA[0] = pack8(x0, y0); bA[1] = pack8(x1, y1);
            const float* dq = desc + (size_t)eBc * 64 + kb;
            float4 p0 = *(const float4*)dq,        q0 = *(const float4*)(dq + 4);
            float4 p1 = *(const float4*)(dq + 32), q1 = *(const float4*)(dq + 36);
            bB[0] = pack8(p0, q0); bB[1] = pack8(p1, q1);
        }

        float* opA = out + (size_t)eA * 64 + g * 4;
        float* opB = out + (size_t)eB * 64 + g * 4;

        #pragma unroll 1
        for (int nt = 0; nt < 4; ++nt) {
            // lin path (m = 10 fragments, unmasked)
            f32x4 zLA, zLB, zWA, zWB;
            {
                const bf16x8 f0 = *(const bf16x8*)(&wsm[((10 * 8 + nt * 2 + 0) * 64 + lane) * 8]);
                const bf16x8 f1 = *(const bf16x8*)(&wsm[((10 * 8 + nt * 2 + 1) * 64 + lane) * 8]);
                f32x4 z = {0.f, 0.f, 0.f, 0.f};
                z = __builtin_amdgcn_mfma_f32_16x16x32_bf16(f0, bA[0], z, 0, 0, 0);
                zLA = __builtin_amdgcn_mfma_f32_16x16x32_bf16(f1, bA[1], z, 0, 0, 0);
                f32x4 y = {0.f, 0.f, 0.f, 0.f};
                y = __builtin_amdgcn_mfma_f32_16x16x32_bf16(f0, bB[0], y, 0, 0, 0);
                zLB = __builtin_amdgcn_mfma_f32_16x16x32_bf16(f1, bB[1], y, 0, 0, 0);
            }
            zWA = (f32x4){0.f, 0.f, 0.f, 0.f};
            zWB = (f32x4){0.f, 0.f, 0.f, 0.f};

            // W path: masked-B accumulation over the 10 types
            #pragma unroll 1
            for (int m = 0; m < 10; ++m) {
                const bf16x8 f0 = *(const bf16x8*)(&wsm[((m * 8 + nt * 2 + 0) * 64 + lane) * 8]);
                const bf16x8 f1 = *(const bf16x8*)(&wsm[((m * 8 + nt * 2 + 1) * 64 + lane) * 8]);
                const bf16x8 mA0 = (tyA == m) ? bA[0] : zero8;
                const bf16x8 mA1 = (tyA == m) ? bA[1] : zero8;
                const bf16x8 mB0 = (tyB == m) ? bB[0] : zero8;
                const bf16x8 mB1 = (tyB == m) ? bB[1] : zero8;
                zWA = __builtin_amdgcn_mfma_f32_16x16x32_bf16(f0, mA0, zWA, 0, 0, 0);
                zWA = __builtin_amdgcn_mfma_f32_16x16x32_bf16(f1, mA1, zWA, 0, 0, 0);
                zWB = __builtin_amdgcn_mfma_f32_16x16x32_bf16(f0, mB0, zWB, 0, 0, 0);
                zWB = __builtin_amdgcn_mfma_f32_16x16x32_bf16(f1, mB1, zWB, 0, 0, 0);
            }

            const float4 bias = *(const float4*)(lin_b + nt * 16 + g * 4);
            if (eA < E) {
                f32x4 r;
                r[0] = ftanh(zWA[0]) + zLA[0] + bias.x;
                r[1] = ftanh(zWA[1]) + zLA[1] + bias.y;
                r[2] = ftanh(zWA[2]) + zLA[2] + bias.z;
                r[3] = ftanh(zWA[3]) + zLA[3] + bias.w;
                *(f32x4*)(opA + nt * 16) = r;
            }
            if (eB < E) {
                f32x4 r;
                r[0] = ftanh(zWB[0]) + zLB[0] + bias.x;
                r[1] = ftanh(zWB[1]) + zLB[1] + bias.y;
                r[2] = ftanh(zWB[2]) + zLB[2] + bias.z;
                r[3] = ftanh(zWB[3]) + zLB[3] + bias.w;
                *(f32x4*)(opB + nt * 16) = r;
            }
        }
    }
}

extern "C" void kernel_launch(void* const* d_in, const int* in_sizes, int n_in,
                              void* d_out, int out_size, void* d_ws, size_t ws_size,
                              hipStream_t stream) {
    const int* ij = (const int*)d_in[0];
    const float* desc = (const float*)d_in[1];
    const float* layer1 = (const float*)d_in[2];
    const float* lin_w = (const float*)d_in[3];
    const float* lin_b = (const float*)d_in[4];
    float* out = (float*)d_out;
    const int E = in_sizes[0];

    k_fused<<<NBLK, 512, 0, stream>>>(ij, desc, layer1, lin_w, lin_b, out, E);
}

// Round 10
// 31.496 us; speedup vs baseline: 9.2277x; 1.0181x over previous
//
#include <hip/hip_runtime.h>
#include <hip/hip_bf16.h>

typedef __attribute__((ext_vector_type(8))) short bf16x8;
typedef __attribute__((ext_vector_type(4))) float f32x4;

#define NBLK 256   // blocks; 512 threads each; 1 block/CU (88 KB LDS)

__device__ __forceinline__ unsigned short f2bf(float f) {
    unsigned u = __float_as_uint(f);
    return (unsigned short)((u + 0x7fffu + ((u >> 16) & 1u)) >> 16);
}

__device__ __forceinline__ bf16x8 pack8(float4 x, float4 y) {
    bf16x8 r;
    r[0] = (short)f2bf(x.x); r[1] = (short)f2bf(x.y);
    r[2] = (short)f2bf(x.z); r[3] = (short)f2bf(x.w);
    r[4] = (short)f2bf(y.x); r[5] = (short)f2bf(y.y);
    r[6] = (short)f2bf(y.z); r[7] = (short)f2bf(y.w);
    return r;
}

__device__ __forceinline__ float ftanh(float x) {
    float e = __expf(2.f * x);
    return 1.f - 2.f / (e + 1.f);
}

// Fused kernel, masked-B accumulation, per-nt outer loop, 64 edges per wave
// pass (4 B-tiles share each fragment ds_read -> half the LDS traffic of the
// 32-edge version). out_e = tanh(Σ_m mfma(W_m, [ty==m]·d)) + (L·d + b).
// Register discipline (rounds 6-9 lesson: live-set > 128 VGPR -> scratch spill
// -> symmetric FETCH/WRITE blowup): per-nt loop keeps 8 f32x4 accs live,
// #pragma unroll 1 on nt/m loops stops ds_read hoisting.
// Fragment layout (verified rounds 1-5): A row = lane&15, k = (lane>>4)*8+j;
// B col = lane&15 (edge), same k; D col = lane&15 (edge), row = (lane>>4)*4+r.
__global__ __launch_bounds__(512, 1) void k_fused(
    const int* __restrict__ ij, const float* __restrict__ desc,
    const float* __restrict__ layer1, const float* __restrict__ lin_w,
    const float* __restrict__ lin_b, float* __restrict__ out, int E) {

    __shared__ __align__(16) short wsm[11 * 512 * 8];   // 88 KiB; m=10 is lin_w

    for (int idx = threadIdx.x; idx < 11 * 512; idx += 512) {
        const int m = idx >> 9;
        const int fl = idx & 511;
        const int fi = fl >> 6, l = fl & 63;
        const int nt = fi >> 1, kk = fi & 1;
        const float* src = (m < 10) ? (layer1 + m * 4096) : lin_w;
        const float* sp = src + (nt * 16 + (l & 15)) * 64 + kk * 32 + (l >> 4) * 8;
        float4 x = *(const float4*)sp;
        float4 y = *(const float4*)(sp + 4);
        *(bf16x8*)(&wsm[idx * 8]) = pack8(x, y);
    }

    const int lane = threadIdx.x & 63;
    const int col = lane & 15;
    const int g = lane >> 4;
    const int kb = g * 8;
    const bf16x8 zero8 = {0, 0, 0, 0, 0, 0, 0, 0};

    __syncthreads();

    const int gw = blockIdx.x * 8 + (threadIdx.x >> 6);
    const int nst = (E + 63) >> 6;       // 64-edge passes; E=131072 -> exactly 1/wave
    for (int s = gw; s < nst; s += NBLK * 8) {
        const int jb = s * 64;
        int e[4], ty[4];
        float4 d0[4], d1[4], d2[4], d3[4];
        #pragma unroll
        for (int p = 0; p < 4; ++p) {
            e[p] = jb + p * 16 + col;
            const int ec = min(e[p], E - 1);
            ty[p] = ij[ec];
            const float* dp = desc + (size_t)ec * 64 + kb;
            d0[p] = *(const float4*)dp;
            d1[p] = *(const float4*)(dp + 4);
            d2[p] = *(const float4*)(dp + 32);
            d3[p] = *(const float4*)(dp + 36);
        }
        bf16x8 b0[4], b1[4];
        #pragma unroll
        for (int p = 0; p < 4; ++p) {
            b0[p] = pack8(d0[p], d1[p]);
            b1[p] = pack8(d2[p], d3[p]);
        }

        #pragma unroll 1
        for (int nt = 0; nt < 4; ++nt) {
            f32x4 zL[4], zW[4];
            {
                const bf16x8 f0 = *(const bf16x8*)(&wsm[((80 + nt * 2 + 0) * 64 + lane) * 8]);
                const bf16x8 f1 = *(const bf16x8*)(&wsm[((80 + nt * 2 + 1) * 64 + lane) * 8]);
                #pragma unroll
                for (int p = 0; p < 4; ++p) {
                    f32x4 z = {0.f, 0.f, 0.f, 0.f};
                    z = __builtin_amdgcn_mfma_f32_16x16x32_bf16(f0, b0[p], z, 0, 0, 0);
                    zL[p] = __builtin_amdgcn_mfma_f32_16x16x32_bf16(f1, b1[p], z, 0, 0, 0);
                    zW[p] = (f32x4){0.f, 0.f, 0.f, 0.f};
                }
            }

            #pragma unroll 1
            for (int m = 0; m < 10; ++m) {
                const bf16x8 f0 = *(const bf16x8*)(&wsm[((m * 8 + nt * 2 + 0) * 64 + lane) * 8]);
                const bf16x8 f1 = *(const bf16x8*)(&wsm[((m * 8 + nt * 2 + 1) * 64 + lane) * 8]);
                #pragma unroll
                for (int p = 0; p < 4; ++p) {
                    const bf16x8 m0 = (ty[p] == m) ? b0[p] : zero8;
                    const bf16x8 m1 = (ty[p] == m) ? b1[p] : zero8;
                    zW[p] = __builtin_amdgcn_mfma_f32_16x16x32_bf16(f0, m0, zW[p], 0, 0, 0);
                    zW[p] = __builtin_amdgcn_mfma_f32_16x16x32_bf16(f1, m1, zW[p], 0, 0, 0);
                }
            }

            const float4 bias = *(const float4*)(lin_b + nt * 16 + g * 4);
            #pragma unroll
            for (int p = 0; p < 4; ++p) {
                if (e[p] < E) {
                    f32x4 r;
                    r[0] = ftanh(zW[p][0]) + zL[p][0] + bias.x;
                    r[1] = ftanh(zW[p][1]) + zL[p][1] + bias.y;
                    r[2] = ftanh(zW[p][2]) + zL[p][2] + bias.z;
                    r[3] = ftanh(zW[p][3]) + zL[p][3] + bias.w;
                    *(f32x4*)(out + (size_t)e[p] * 64 + nt * 16 + g * 4) = r;
                }
            }
        }
    }
}

extern "C" void kernel_launch(void* const* d_in, const int* in_sizes, int n_in,
                              void* d_out, int out_size, void* d_ws, size_t ws_size,
                              hipStream_t stream) {
    const int* ij = (const int*)d_in[0];
    const float* desc = (const float*)d_in[1];
    const float* layer1 = (const float*)d_in[2];
    const float* lin_w = (const float*)d_in[3];
    const float* lin_b = (const float*)d_in[4];
    float* out = (float*)d_out;
    const int E = in_sizes[0];

    k_fused<<<NBLK, 512, 0, stream>>>(ij, desc, layer1, lin_w, lin_b, out, E);
}

// Round 11
// 30.018 us; speedup vs baseline: 9.6822x; 1.0493x over previous
//
#include <hip/hip_runtime.h>
#include <hip/hip_bf16.h>

typedef __attribute__((ext_vector_type(8))) short bf16x8;
typedef __attribute__((ext_vector_type(4))) float f32x4;

#define NBLK 256   // blocks; 1024 threads each; 1 block/CU (88 KB LDS), 4 waves/SIMD

__device__ __forceinline__ unsigned short f2bf(float f) {
    unsigned u = __float_as_uint(f);
    return (unsigned short)((u + 0x7fffu + ((u >> 16) & 1u)) >> 16);
}

__device__ __forceinline__ bf16x8 pack8(float4 x, float4 y) {
    bf16x8 r;
    r[0] = (short)f2bf(x.x); r[1] = (short)f2bf(x.y);
    r[2] = (short)f2bf(x.z); r[3] = (short)f2bf(x.w);
    r[4] = (short)f2bf(y.x); r[5] = (short)f2bf(y.y);
    r[6] = (short)f2bf(y.z); r[7] = (short)f2bf(y.w);
    return r;
}

__device__ __forceinline__ float ftanh(float x) {
    float e = __expf(2.f * x);
    return 1.f - 2.f / (e + 1.f);
}

// Fused kernel, masked-B accumulation, per-nt outer loop, 32 edges/wave,
// 1024-thread blocks (16 waves) -> 4 waves/SIMD (was 2: R10 measured ~29 us
// kernel at 2 waves/SIMD; loads/compute phase-separated per wave, so memory
// idles unless other waves fill it -> occupancy is the lever this round).
// out_e = tanh(Σ_m mfma(W_m, [ty==m]·d)) + (L·d + b).
// Register discipline (rounds 6-9 lesson: live-set > 128 VGPR -> scratch spill
// -> symmetric FETCH/WRITE blowup): per-nt loop keeps 4 f32x4 accs live,
// #pragma unroll 1 on nt/m loops stops ds_read hoisting.
// Fragment layout (verified rounds 1-5): A row = lane&15, k = (lane>>4)*8+j;
// B col = lane&15 (edge), same k; D col = lane&15 (edge), row = (lane>>4)*4+r.
__global__ __launch_bounds__(1024, 4) void k_fused(
    const int* __restrict__ ij, const float* __restrict__ desc,
    const float* __restrict__ layer1, const float* __restrict__ lin_w,
    const float* __restrict__ lin_b, float* __restrict__ out, int E) {

    __shared__ __align__(16) short wsm[11 * 512 * 8];   // 88 KiB; m=10 is lin_w

    for (int idx = threadIdx.x; idx < 11 * 512; idx += 1024) {
        const int m = idx >> 9;
        const int fl = idx & 511;
        const int fi = fl >> 6, l = fl & 63;
        const int nt = fi >> 1, kk = fi & 1;
        const float* src = (m < 10) ? (layer1 + m * 4096) : lin_w;
        const float* sp = src + (nt * 16 + (l & 15)) * 64 + kk * 32 + (l >> 4) * 8;
        float4 x = *(const float4*)sp;
        float4 y = *(const float4*)(sp + 4);
        *(bf16x8*)(&wsm[idx * 8]) = pack8(x, y);
    }

    const int lane = threadIdx.x & 63;
    const int col = lane & 15;
    const int g = lane >> 4;
    const int kb = g * 8;
    const bf16x8 zero8 = {0, 0, 0, 0, 0, 0, 0, 0};

    __syncthreads();

    const int gw = blockIdx.x * 16 + (threadIdx.x >> 6);
    const int nst = (E + 31) >> 5;       // 32-edge supertiles; E=131072 -> exactly 1/wave
    for (int s = gw; s < nst; s += NBLK * 16) {
        const int jb = s * 32;
        int e[2], ty[2];
        float4 d0[2], d1[2], d2[2], d3[2];
        #pragma unroll
        for (int p = 0; p < 2; ++p) {
            e[p] = jb + p * 16 + col;
            const int ec = min(e[p], E - 1);
            ty[p] = ij[ec];
            const float* dp = desc + (size_t)ec * 64 + kb;
            d0[p] = *(const float4*)dp;
            d1[p] = *(const float4*)(dp + 4);
            d2[p] = *(const float4*)(dp + 32);
            d3[p] = *(const float4*)(dp + 36);
        }
        bf16x8 b0[2], b1[2];
        #pragma unroll
        for (int p = 0; p < 2; ++p) {
            b0[p] = pack8(d0[p], d1[p]);
            b1[p] = pack8(d2[p], d3[p]);
        }

        #pragma unroll 1
        for (int nt = 0; nt < 4; ++nt) {
            f32x4 zL[2], zW[2];
            {
                const bf16x8 f0 = *(const bf16x8*)(&wsm[((80 + nt * 2 + 0) * 64 + lane) * 8]);
                const bf16x8 f1 = *(const bf16x8*)(&wsm[((80 + nt * 2 + 1) * 64 + lane) * 8]);
                #pragma unroll
                for (int p = 0; p < 2; ++p) {
                    f32x4 z = {0.f, 0.f, 0.f, 0.f};
                    z = __builtin_amdgcn_mfma_f32_16x16x32_bf16(f0, b0[p], z, 0, 0, 0);
                    zL[p] = __builtin_amdgcn_mfma_f32_16x16x32_bf16(f1, b1[p], z, 0, 0, 0);
                    zW[p] = (f32x4){0.f, 0.f, 0.f, 0.f};
                }
            }

            #pragma unroll 1
            for (int m = 0; m < 10; ++m) {
                const bf16x8 f0 = *(const bf16x8*)(&wsm[((m * 8 + nt * 2 + 0) * 64 + lane) * 8]);
                const bf16x8 f1 = *(const bf16x8*)(&wsm[((m * 8 + nt * 2 + 1) * 64 + lane) * 8]);
                #pragma unroll
                for (int p = 0; p < 2; ++p) {
                    const bf16x8 m0 = (ty[p] == m) ? b0[p] : zero8;
                    const bf16x8 m1 = (ty[p] == m) ? b1[p] : zero8;
                    zW[p] = __builtin_amdgcn_mfma_f32_16x16x32_bf16(f0, m0, zW[p], 0, 0, 0);
                    zW[p] = __builtin_amdgcn_mfma_f32_16x16x32_bf16(f1, m1, zW[p], 0, 0, 0);
                }
            }

            const float4 bias = *(const float4*)(lin_b + nt * 16 + g * 4);
            #pragma unroll
            for (int p = 0; p < 2; ++p) {
                if (e[p] < E) {
                    f32x4 r;
                    r[0] = ftanh(zW[p][0]) + zL[p][0] + bias.x;
                    r[1] = ftanh(zW[p][1]) + zL[p][1] + bias.y;
                    r[2] = ftanh(zW[p][2]) + zL[p][2] + bias.z;
                    r[3] = ftanh(zW[p][3]) + zL[p][3] + bias.w;
                    *(f32x4*)(out + (size_t)e[p] * 64 + nt * 16 + g * 4) = r;
                }
            }
        }
    }
}

extern "C" void kernel_launch(void* const* d_in, const int* in_sizes, int n_in,
                              void* d_out, int out_size, void* d_ws, size_t ws_size,
                              hipStream_t stream) {
    const int* ij = (const int*)d_in[0];
    const float* desc = (const float*)d_in[1];
    const float* layer1 = (const float*)d_in[2];
    const float* lin_w = (const float*)d_in[3];
    const float* lin_b = (const float*)d_in[4];
    float* out = (float*)d_out;
    const int E = in_sizes[0];

    k_fused<<<NBLK, 1024, 0, stream>>>(ij, desc, layer1, lin_w, lin_b, out, E);
}